// Round 1
// baseline (2289.769 us; speedup 1.0000x reference)
//
#include <hip/hip_runtime.h>
#include <hip/hip_bf16.h>

#define HID     256
#define NNODES  50000
#define NEDGES  300000
#define NGRAPHS 128
#define L       4

// ---------------------------------------------------------------- node embed
// h[n][j] = sum_k x[n][k] * node_w[k][j] + node_b[j]   (K=32)
__global__ void node_embed_k(const float* __restrict__ x,
                             const float* __restrict__ w,
                             const float* __restrict__ b,
                             float* __restrict__ h) {
    int n = blockIdx.x;
    int j = threadIdx.x;
    __shared__ float xr[32];
    if (j < 32) xr[j] = x[n * 32 + j];
    __syncthreads();
    float acc = b[j];
#pragma unroll
    for (int k = 0; k < 32; ++k) acc = fmaf(xr[k], w[k * HID + j], acc);
    h[n * HID + j] = acc;
}

// ------------------------------------------------------- message + scatter
// agg[dst] += relu(h[src] + edge_attr[e] @ edge_w + edge_b), ea on the fly.
#define EPB 64
__global__ void msg_scatter_k(const float* __restrict__ h,
                              const float* __restrict__ eattr,
                              const int* __restrict__ ei,
                              const float* __restrict__ ew,
                              const float* __restrict__ eb,
                              float* __restrict__ agg) {
    __shared__ float wsh[16 * HID];
    __shared__ float ebs[HID];
    int j = threadIdx.x;
    for (int i = j; i < 16 * HID; i += 256) wsh[i] = ew[i];
    ebs[j] = eb[j];
    __syncthreads();
    int e0   = blockIdx.x * EPB;
    int eend = min(e0 + EPB, NEDGES);
    for (int e = e0; e < eend; ++e) {
        int s = ei[e];
        int d = ei[NEDGES + e];
        float acc = ebs[j];
#pragma unroll
        for (int k = 0; k < 16; ++k)
            acc = fmaf(eattr[e * 16 + k], wsh[k * HID + j], acc);
        float v = h[s * HID + j] + acc;
        v = fmaxf(v, 0.f);
        atomicAdd(&agg[d * HID + j], v);
    }
}

// ------------------------------------------------------------------- GEMM
// C[M,256] = act( (A (+A2)) @ W[256,256] + bias )
// tile 64x64, TK=16, 256 threads (16x16), 4x4 per thread, fp32.
template <bool ADD2, bool RELU>
__global__ void gemm256_k(const float* __restrict__ A,
                          const float* __restrict__ A2,
                          const float* __restrict__ W,
                          const float* __restrict__ bias,
                          float* __restrict__ C, int M) {
    __shared__ float As[16][68];
    __shared__ float Bs[16][68];
    int bm = blockIdx.x * 64;
    int bn = blockIdx.y * 64;
    int tx = threadIdx.x % 16;
    int ty = threadIdx.x / 16;

    // staging indices
    int tmA = threadIdx.x / 4;        // 0..63 : tile row for A load
    int tkA = (threadIdx.x % 4) * 4;  // 0,4,8,12 : k offset (float4)
    int tkB = threadIdx.x / 16;       // 0..15 : k row for B load
    int tnB = (threadIdx.x % 16) * 4; // 0..60 : n offset (float4)

    float acc[4][4] = {};

    for (int k0 = 0; k0 < 256; k0 += 16) {
        __syncthreads();
        // A tile (64 x 16), with optional elementwise add of A2
        {
            int gr = bm + tmA;
            float4 av = make_float4(0.f, 0.f, 0.f, 0.f);
            if (gr < M) {
                av = *reinterpret_cast<const float4*>(A + gr * 256 + k0 + tkA);
                if (ADD2) {
                    float4 bv = *reinterpret_cast<const float4*>(A2 + gr * 256 + k0 + tkA);
                    av.x += bv.x; av.y += bv.y; av.z += bv.z; av.w += bv.w;
                }
            }
            As[tkA + 0][tmA] = av.x;
            As[tkA + 1][tmA] = av.y;
            As[tkA + 2][tmA] = av.z;
            As[tkA + 3][tmA] = av.w;
        }
        // B tile (16 x 64)
        {
            float4 bv = *reinterpret_cast<const float4*>(W + (k0 + tkB) * 256 + bn + tnB);
            Bs[tkB][tnB + 0] = bv.x;
            Bs[tkB][tnB + 1] = bv.y;
            Bs[tkB][tnB + 2] = bv.z;
            Bs[tkB][tnB + 3] = bv.w;
        }
        __syncthreads();
#pragma unroll
        for (int k = 0; k < 16; ++k) {
            float a[4], b[4];
#pragma unroll
            for (int i = 0; i < 4; ++i) a[i] = As[k][ty * 4 + i];
#pragma unroll
            for (int jj = 0; jj < 4; ++jj) b[jj] = Bs[k][tx * 4 + jj];
#pragma unroll
            for (int i = 0; i < 4; ++i)
#pragma unroll
                for (int jj = 0; jj < 4; ++jj)
                    acc[i][jj] = fmaf(a[i], b[jj], acc[i][jj]);
        }
    }

#pragma unroll
    for (int i = 0; i < 4; ++i) {
        int r = bm + ty * 4 + i;
        if (r < M) {
            float4 c;
            float* cp = &c.x;
#pragma unroll
            for (int jj = 0; jj < 4; ++jj) {
                float v = acc[i][jj] + bias[bn + tx * 4 + jj];
                if (RELU) v = fmaxf(v, 0.f);
                cp[jj] = v;
            }
            *reinterpret_cast<float4*>(C + r * 256 + bn + tx * 4) = c;
        }
    }
}

// ------------------------------------------------------------- BN stats
__global__ void stats_k(const float* __restrict__ z, float* __restrict__ stats) {
    int j = threadIdx.x;
    int rows = (NNODES + gridDim.x - 1) / gridDim.x;
    int r0 = blockIdx.x * rows;
    int r1 = min(r0 + rows, NNODES);
    float s = 0.f, ss = 0.f;
    for (int r = r0; r < r1; ++r) {
        float v = z[r * HID + j];
        s += v;
        ss = fmaf(v, v, ss);
    }
    atomicAdd(&stats[j], s);
    atomicAdd(&stats[HID + j], ss);
}

// ------------------------------------------------------- BN normalize+relu
__global__ void bn_relu_k(float* __restrict__ z, const float* __restrict__ stats,
                          const float* __restrict__ gamma,
                          const float* __restrict__ beta) {
    int idx = blockIdx.x * 256 + threadIdx.x;
    int j = threadIdx.x; // == idx % 256 since blockDim=256 and HID=256
    float mu  = stats[j] * (1.f / NNODES);
    float var = stats[HID + j] * (1.f / NNODES) - mu * mu;
    float inv = rsqrtf(var + 1e-5f);
    float v = (z[idx] - mu) * inv * gamma[j] + beta[j];
    z[idx] = fmaxf(v, 0.f);
}

// ------------------------------------------------------------------ pool
__global__ void pool_k(const float* __restrict__ h, const int* __restrict__ batch,
                       float* __restrict__ g) {
    int n = blockIdx.x;
    int j = threadIdx.x;
    atomicAdd(&g[batch[n] * HID + j], h[n * HID + j]);
}

// ------------------------------------------------------------------ head
__global__ void head_k(const float* __restrict__ g, const float* __restrict__ w1,
                       const float* __restrict__ b1, const float* __restrict__ w2,
                       const float* __restrict__ b2, float* __restrict__ out) {
    int gi = blockIdx.x;  // 0..127
    int j  = threadIdx.x; // 0..127
    __shared__ float gr[256];
    __shared__ float hid[128];
    gr[j]       = g[gi * 256 + j];
    gr[j + 128] = g[gi * 256 + 128 + j];
    __syncthreads();
    float acc = b1[j];
    for (int k = 0; k < 256; ++k) acc = fmaf(gr[k], w1[k * 128 + j], acc);
    hid[j] = fmaxf(acc, 0.f);
    __syncthreads();
    if (j < 12) {
        float o = b2[j];
#pragma unroll
        for (int k = 0; k < 128; ++k) o = fmaf(hid[k], w2[k * 12 + j], o);
        out[gi * 12 + j] = o;
    }
}

// ---------------------------------------------------------------- launch
extern "C" void kernel_launch(void* const* d_in, const int* in_sizes, int n_in,
                              void* d_out, int out_size, void* d_ws, size_t ws_size,
                              hipStream_t stream) {
    const float* x     = (const float*)d_in[0];
    const int*   ei    = (const int*)d_in[1];
    const int*   batch = (const int*)d_in[2];
    const float* eattr = (const float*)d_in[3];
    const float* nw    = (const float*)d_in[4];
    const float* nb    = (const float*)d_in[5];
    const float* ew    = (const float*)d_in[6];
    const float* eb    = (const float*)d_in[7];
    const float* w1    = (const float*)d_in[8];
    const float* b1    = (const float*)d_in[9];
    const float* w2    = (const float*)d_in[10];
    const float* b2    = (const float*)d_in[11];
    const float* gam   = (const float*)d_in[12];
    const float* bet   = (const float*)d_in[13];
    const float* hw1   = (const float*)d_in[14];
    const float* hb1   = (const float*)d_in[15];
    const float* hw2   = (const float*)d_in[16];
    const float* hb2   = (const float*)d_in[17];
    float* out = (float*)d_out;

    const size_t NH = (size_t)NNODES * HID; // 12.8M
    float* h     = (float*)d_ws;
    float* agg   = h + NH;
    float* z1    = agg + NH;
    float* stats = z1 + NH;
    float* g     = stats + 2 * HID;

    // node / edge embedding
    node_embed_k<<<NNODES, 256, 0, stream>>>(x, nw, nb, h);

    dim3 ggrid((NNODES + 63) / 64, 4);
    for (int l = 0; l < L; ++l) {
        hipMemsetAsync(agg, 0, NH * sizeof(float), stream);
        msg_scatter_k<<<(NEDGES + EPB - 1) / EPB, 256, 0, stream>>>(
            h, eattr, ei, ew, eb, agg);
        gemm256_k<true, true><<<ggrid, 256, 0, stream>>>(
            h, agg, w1 + (size_t)l * HID * HID, b1 + l * HID, z1, NNODES);
        gemm256_k<false, false><<<ggrid, 256, 0, stream>>>(
            z1, nullptr, w2 + (size_t)l * HID * HID, b2 + l * HID, h, NNODES);
        hipMemsetAsync(stats, 0, 2 * HID * sizeof(float), stream);
        stats_k<<<512, 256, 0, stream>>>(h, stats);
        bn_relu_k<<<NNODES, 256, 0, stream>>>(h, stats, gam + l * HID, bet + l * HID);
    }

    hipMemsetAsync(g, 0, (size_t)NGRAPHS * HID * sizeof(float), stream);
    pool_k<<<NNODES, 256, 0, stream>>>(h, batch, g);
    head_k<<<NGRAPHS, 128, 0, stream>>>(g, hw1, hb1, hw2, hb2, out);
}

// Round 2
// 1474.296 us; speedup vs baseline: 1.5531x; 1.5531x over previous
//
#include <hip/hip_runtime.h>
#include <hip/hip_bf16.h>

#define HID     256
#define NNODES  50000
#define NEDGES  300000
#define NGRAPHS 128
#define L       4

typedef __attribute__((ext_vector_type(8))) short bf16x8;
typedef __attribute__((ext_vector_type(4))) float f32x4;

static __device__ __forceinline__ float b2f(short s) {
    union { unsigned u; float f; } v;
    v.u = ((unsigned)(unsigned short)s) << 16;
    return v.f;
}
static __device__ __forceinline__ short f2b(float f) {
    __hip_bfloat16 h = __float2bfloat16(f);
    return *reinterpret_cast<short*>(&h);
}

// ------------------------------------------------ weight convert + transpose
// wT[m][n][k] = w[m][k][n]  (4 matrices per call), fp32 -> bf16
__global__ void wconv_k(const float* __restrict__ w, short* __restrict__ wT) {
    int m = blockIdx.y, n = blockIdx.x, k = threadIdx.x;
    wT[(size_t)m * 65536 + n * 256 + k] = f2b(w[(size_t)m * 65536 + k * 256 + n]);
}

// ---------------------------------------------------------------- node embed
__global__ void node_embed_k(const float* __restrict__ x,
                             const float* __restrict__ w,
                             const float* __restrict__ b,
                             short* __restrict__ hb) {
    int n = blockIdx.x;
    int j = threadIdx.x;
    __shared__ float xr[32];
    if (j < 32) xr[j] = x[n * 32 + j];
    __syncthreads();
    float acc = b[j];
#pragma unroll
    for (int k = 0; k < 32; ++k) acc = fmaf(xr[k], w[k * HID + j], acc);
    hb[(size_t)n * HID + j] = f2b(acc);
}

// ------------------------------------------------------------- CSR building
__global__ void deg_k(const int* __restrict__ ei, int* __restrict__ deg) {
    int e = blockIdx.x * 256 + threadIdx.x;
    if (e < NEDGES) atomicAdd(&deg[ei[NEDGES + e]], 1);
}

__global__ void scan1_k(const int* __restrict__ deg, int* __restrict__ partial,
                        int* __restrict__ btot) {
    __shared__ int s[256];
    int t = threadIdx.x;
    int gi = blockIdx.x * 256 + t;
    s[t] = (gi < NNODES) ? deg[gi] : 0;
    __syncthreads();
    for (int off = 1; off < 256; off <<= 1) {
        int u = (t >= off) ? s[t - off] : 0;
        __syncthreads();
        s[t] += u;
        __syncthreads();
    }
    if (gi < NNODES) partial[gi] = s[t];
    if (t == 255) btot[blockIdx.x] = s[255];
}

__global__ void scan2_k(int* __restrict__ btot, int nb) {
    __shared__ int s[256];
    int t = threadIdx.x;
    s[t] = (t < nb) ? btot[t] : 0;
    __syncthreads();
    for (int off = 1; off < 256; off <<= 1) {
        int u = (t >= off) ? s[t - off] : 0;
        __syncthreads();
        s[t] += u;
        __syncthreads();
    }
    btot[t] = s[t];
}

__global__ void scan3_k(const int* __restrict__ deg, const int* __restrict__ partial,
                        const int* __restrict__ btot, int* __restrict__ row_ptr,
                        int* __restrict__ cursor) {
    int gi = blockIdx.x * 256 + threadIdx.x;
    if (gi >= NNODES) return;
    int b = blockIdx.x;
    int incl = partial[gi] + (b ? btot[b - 1] : 0);
    int start = incl - deg[gi];
    row_ptr[gi] = start;
    cursor[gi] = start;
    if (gi == NNODES - 1) row_ptr[NNODES] = incl;
}

__global__ void fill_k(const int* __restrict__ ei, int* __restrict__ cursor,
                       int* __restrict__ eid) {
    int e = blockIdx.x * 256 + threadIdx.x;
    if (e < NEDGES) {
        int d = ei[NEDGES + e];
        int pos = atomicAdd(&cursor[d], 1);
        eid[pos] = e;
    }
}

// -------------------------------------------------- CSR aggregate (no atomics)
// zb[n] = hb[n] + sum_{e: dst=n} relu(hb[src] + eattr[e]@ew + eb)   (bf16 out)
#define NPB 16
__global__ __launch_bounds__(256) void aggregate_k(
    const short* __restrict__ hb, const float* __restrict__ eattr,
    const int* __restrict__ ei, const int* __restrict__ row_ptr,
    const int* __restrict__ eid, const float* __restrict__ ew,
    const float* __restrict__ eb, short* __restrict__ zb) {
    __shared__ float wsh[16 * HID];
    __shared__ float ebs[HID];
    int j = threadIdx.x;
    for (int i = j; i < 16 * HID; i += 256) wsh[i] = ew[i];
    ebs[j] = eb[j];
    __syncthreads();
    int n0 = blockIdx.x * NPB;
    int n1 = min(n0 + NPB, NNODES);
    for (int n = n0; n < n1; ++n) {
        float acc = b2f(hb[(size_t)n * HID + j]);
        int beg = row_ptr[n], end = row_ptr[n + 1];
        for (int t = beg; t < end; ++t) {
            int e = eid[t];
            int s = ei[e];
            float m = ebs[j];
            const float* ea = eattr + (size_t)e * 16;
#pragma unroll
            for (int k = 0; k < 16; ++k) m = fmaf(ea[k], wsh[k * HID + j], m);
            m += b2f(hb[(size_t)s * HID + j]);
            acc += fmaxf(m, 0.f);
        }
        zb[(size_t)n * HID + j] = f2b(acc);
    }
}

// ----------------------------------------------------------- bf16 MFMA GEMM
// C[M,256] = act(A[M,256] @ W + bias); A bf16 row-major, wT[n][k] bf16.
// block = 4 waves, each wave 32 rows x 64 cols; grid (ceil(M/128), 4).
template <bool RELU, bool OUTBF16>
__global__ __launch_bounds__(256) void gemm_k(const short* __restrict__ A,
                                              const short* __restrict__ wT,
                                              const float* __restrict__ bias,
                                              void* __restrict__ Cout, int M) {
    int wv = threadIdx.x >> 6, lane = threadIdx.x & 63;
    int lr = lane & 15, lg = lane >> 4;
    int r0 = blockIdx.x * 128 + wv * 32;
    int c0 = blockIdx.y * 64;

    int rA0 = r0 + lr, rA1 = r0 + 16 + lr;
    bool g0 = rA0 < M, g1 = rA1 < M;
    const short* pA0 = A + (size_t)rA0 * 256 + lg * 8;
    const short* pA1 = A + (size_t)rA1 * 256 + lg * 8;
    const short* pB = wT + (size_t)(c0 + lr) * 256 + lg * 8;

    f32x4 acc[2][4] = {};

    for (int k0 = 0; k0 < 256; k0 += 32) {
        bf16x8 a0 = {}, a1 = {};
        if (g0) a0 = *reinterpret_cast<const bf16x8*>(pA0 + k0);
        if (g1) a1 = *reinterpret_cast<const bf16x8*>(pA1 + k0);
#pragma unroll
        for (int c = 0; c < 4; ++c) {
            bf16x8 b = *reinterpret_cast<const bf16x8*>(pB + c * 16 * 256 + k0);
            acc[0][c] = __builtin_amdgcn_mfma_f32_16x16x32_bf16(a0, b, acc[0][c], 0, 0, 0);
            acc[1][c] = __builtin_amdgcn_mfma_f32_16x16x32_bf16(a1, b, acc[1][c], 0, 0, 0);
        }
    }

#pragma unroll
    for (int r = 0; r < 2; ++r)
#pragma unroll
        for (int c = 0; c < 4; ++c) {
            int col = c0 + c * 16 + lr;
            float bi = bias[col];
#pragma unroll
            for (int i = 0; i < 4; ++i) {
                int row = r0 + r * 16 + lg * 4 + i;
                if (row < M) {
                    float v = acc[r][c][i] + bi;
                    if (RELU) v = fmaxf(v, 0.f);
                    if (OUTBF16)
                        ((short*)Cout)[(size_t)row * 256 + col] = f2b(v);
                    else
                        ((float*)Cout)[(size_t)row * 256 + col] = v;
                }
            }
        }
}

// ------------------------------------------------------------- BN stats
__global__ void stats_k(const float* __restrict__ z, float* __restrict__ stats) {
    int j = threadIdx.x;
    int rows = (NNODES + gridDim.x - 1) / gridDim.x;
    int r0 = blockIdx.x * rows;
    int r1 = min(r0 + rows, NNODES);
    float s = 0.f, ss = 0.f;
    for (int r = r0; r < r1; ++r) {
        float v = z[(size_t)r * HID + j];
        s += v;
        ss = fmaf(v, v, ss);
    }
    atomicAdd(&stats[j], s);
    atomicAdd(&stats[HID + j], ss);
}

// ------------------------------------------------------- BN normalize+relu
__global__ void bn_relu_k(const float* __restrict__ zf, short* __restrict__ hb,
                          const float* __restrict__ stats,
                          const float* __restrict__ gamma,
                          const float* __restrict__ beta) {
    int idx = blockIdx.x * 256 + threadIdx.x;
    int j = threadIdx.x;
    float mu = stats[j] * (1.f / NNODES);
    float var = stats[HID + j] * (1.f / NNODES) - mu * mu;
    float inv = rsqrtf(var + 1e-5f);
    float v = (zf[idx] - mu) * inv * gamma[j] + beta[j];
    hb[idx] = f2b(fmaxf(v, 0.f));
}

// ------------------------------------------------------------------ pool
__global__ void pool_k(const short* __restrict__ hb, const int* __restrict__ batch,
                       float* __restrict__ g) {
    int n = blockIdx.x;
    int j = threadIdx.x;
    atomicAdd(&g[batch[n] * HID + j], b2f(hb[(size_t)n * HID + j]));
}

// ------------------------------------------------------------------ head
__global__ void head_k(const float* __restrict__ g, const float* __restrict__ w1,
                       const float* __restrict__ b1, const float* __restrict__ w2,
                       const float* __restrict__ b2, float* __restrict__ out) {
    int gi = blockIdx.x;
    int j  = threadIdx.x;
    __shared__ float gr[256];
    __shared__ float hid[128];
    gr[j]       = g[gi * 256 + j];
    gr[j + 128] = g[gi * 256 + 128 + j];
    __syncthreads();
    float acc = b1[j];
    for (int k = 0; k < 256; ++k) acc = fmaf(gr[k], w1[k * 128 + j], acc);
    hid[j] = fmaxf(acc, 0.f);
    __syncthreads();
    if (j < 12) {
        float o = b2[j];
#pragma unroll
        for (int k = 0; k < 128; ++k) o = fmaf(hid[k], w2[k * 12 + j], o);
        out[gi * 12 + j] = o;
    }
}

// ---------------------------------------------------------------- launch
extern "C" void kernel_launch(void* const* d_in, const int* in_sizes, int n_in,
                              void* d_out, int out_size, void* d_ws, size_t ws_size,
                              hipStream_t stream) {
    const float* x     = (const float*)d_in[0];
    const int*   ei    = (const int*)d_in[1];
    const int*   batch = (const int*)d_in[2];
    const float* eattr = (const float*)d_in[3];
    const float* nw    = (const float*)d_in[4];
    const float* nb    = (const float*)d_in[5];
    const float* ew    = (const float*)d_in[6];
    const float* eb    = (const float*)d_in[7];
    const float* w1    = (const float*)d_in[8];
    const float* b1    = (const float*)d_in[9];
    const float* w2    = (const float*)d_in[10];
    const float* b2    = (const float*)d_in[11];
    const float* gam   = (const float*)d_in[12];
    const float* bet   = (const float*)d_in[13];
    const float* hw1   = (const float*)d_in[14];
    const float* hb1   = (const float*)d_in[15];
    const float* hw2   = (const float*)d_in[16];
    const float* hb2   = (const float*)d_in[17];
    float* out = (float*)d_out;

    const size_t NH = (size_t)NNODES * HID;
    size_t off = 0;
    char* base = (char*)d_ws;
    auto alloc = [&](size_t bytes) -> void* {
        void* p = base + off;
        off += (bytes + 255) & ~(size_t)255;
        return p;
    };
    float* zf      = (float*)alloc(NH * 4);
    short* hb      = (short*)alloc(NH * 2);
    short* zb      = (short*)alloc(NH * 2);
    short* z1b     = (short*)alloc(NH * 2);
    short* wT      = (short*)alloc(8 * 65536 * 2);
    float* stats   = (float*)alloc(512 * 4);
    float* g       = (float*)alloc((size_t)NGRAPHS * HID * 4);
    int*   deg     = (int*)alloc((size_t)NNODES * 4);
    int*   partial = (int*)alloc((size_t)NNODES * 4);
    int*   btot    = (int*)alloc(256 * 4);
    int*   row_ptr = (int*)alloc((size_t)(NNODES + 1) * 4);
    int*   cursor  = (int*)alloc((size_t)NNODES * 4);
    int*   eid     = (int*)alloc((size_t)NEDGES * 4);

    // weights -> bf16 transposed
    wconv_k<<<dim3(256, 4), 256, 0, stream>>>(w1, wT);
    wconv_k<<<dim3(256, 4), 256, 0, stream>>>(w2, wT + 4 * 65536);

    // node embedding (bf16 h)
    node_embed_k<<<NNODES, 256, 0, stream>>>(x, nw, nb, hb);

    // CSR build
    hipMemsetAsync(deg, 0, (size_t)NNODES * 4, stream);
    deg_k<<<(NEDGES + 255) / 256, 256, 0, stream>>>(ei, deg);
    const int NB = (NNODES + 255) / 256; // 196
    scan1_k<<<NB, 256, 0, stream>>>(deg, partial, btot);
    scan2_k<<<1, 256, 0, stream>>>(btot, NB);
    scan3_k<<<NB, 256, 0, stream>>>(deg, partial, btot, row_ptr, cursor);
    fill_k<<<(NEDGES + 255) / 256, 256, 0, stream>>>(ei, cursor, eid);

    dim3 ggrid((NNODES + 127) / 128, 4);
    for (int l = 0; l < L; ++l) {
        aggregate_k<<<(NNODES + NPB - 1) / NPB, 256, 0, stream>>>(
            hb, eattr, ei, row_ptr, eid, ew, eb, zb);
        gemm_k<true, true><<<ggrid, 256, 0, stream>>>(
            zb, wT + (size_t)l * 65536, b1 + l * HID, z1b, NNODES);
        gemm_k<false, false><<<ggrid, 256, 0, stream>>>(
            z1b, wT + (size_t)(4 + l) * 65536, b2 + l * HID, zf, NNODES);
        hipMemsetAsync(stats, 0, 512 * 4, stream);
        stats_k<<<512, 256, 0, stream>>>(zf, stats);
        bn_relu_k<<<NNODES, 256, 0, stream>>>(zf, hb, stats, gam + l * HID, bet + l * HID);
    }

    hipMemsetAsync(g, 0, (size_t)NGRAPHS * HID * 4, stream);
    pool_k<<<NNODES, 256, 0, stream>>>(hb, batch, g);
    head_k<<<NGRAPHS, 128, 0, stream>>>(g, hw1, hb1, hw2, hb2, out);
}